// Round 1
// 219.183 us; speedup vs baseline: 1.0189x; 1.0189x over previous
//
#include <hip/hip_runtime.h>

#define DEVINL __device__ __forceinline__

constexpr int Bc = 32, Cc = 64, Tc = 1024, DIM2c = 128;
constexpr int Nn = Bc * Tc;            // 32768 nodes
constexpr int Ec = 524288;             // edges (self-loops handled in-kernel)

typedef __bf16 bf16x8 __attribute__((ext_vector_type(8)));
typedef float  f32x4  __attribute__((ext_vector_type(4)));

// workspace layout (float offsets)
constexpr long O_RES   = 0;            // 4194304 fp32
constexpr long O_GOUT  = 4194304;      // bf16 pairs: 2097152 uints used
constexpr long O_XLQ   = 10485760;     // 2097152 uint (head-split bf16, u16[n][128])
constexpr long O_XRQ   = 12582912;     // 2097152 uint
constexpr long O_Z     = 16777216;     // bf16 pairs: 2097152 uints used
constexpr long O_WCBF  = 20971520;     // bf16 x 73728: [kk][co][ci]
constexpr long O_WLR   = 21008384;     // bf16 x 16384: [j 256][c 64]
constexpr long O_CHB   = 21016576;     // bf16 x 16384: [j 128][c 128]
constexpr long O_STAT  = 21024768;     // 1024 (zeroed by memset)
constexpr long O_CUR   = 21025792;     // 32768 ints (zeroed, contiguous w/ STAT)
constexpr long O_BUCK  = 21058560;     // 2097152 ints

DEVINL float unpack_lo(unsigned v) { return __uint_as_float(v << 16); }
DEVINL float unpack_hi(unsigned v) { return __uint_as_float(v & 0xffff0000u); }
DEVINL unsigned bfb(float f) { return (__float_as_uint(f) + 0x8000u) >> 16; }
DEVINL unsigned pk2(float lo, float hi) {
    return ((__float_as_uint(hi) + 0x8000u) & 0xffff0000u) | bfb(lo);
}

// ================= setup = prep_w U bn0_sums U bucket_fill =================
__global__ __launch_bounds__(256) void setup(const float* __restrict__ x,
        const float* __restrict__ cw, const float* __restrict__ wl,
        const float* __restrict__ wr, const float* __restrict__ chw,
        const int* __restrict__ ei,
        __bf16* __restrict__ wcbf, __bf16* __restrict__ wlrbf,
        __bf16* __restrict__ chwbf,
        float* __restrict__ sum0, float* __restrict__ sq0,
        int* __restrict__ cursor, int* __restrict__ bucket) {
    int bid = blockIdx.x, tid = threadIdx.x;
    if (bid < 416) {                           // weight prep (106496 items exactly)
        int i = bid * 256 + tid;
        if (i < 73728) {                       // wcbf[kk][co][ci] = cw[co][ci*9+kk]
            int kk = i >> 13, co = (i >> 6) & 127, ci = i & 63;
            wcbf[i] = (__bf16)cw[co * 576 + ci * 9 + kk];
        } else if (i < 73728 + 16384) {        // wlrbf[j][c]
            int j = i - 73728;
            int r = j >> 6, c = j & 63;
            float v = (r < 128) ? wl[r * 64 + c] : wr[(r - 128) * 64 + c];
            wlrbf[j] = (__bf16)v;
        } else {                               // chwbf[j][c]
            int j = i - 73728 - 16384;
            chwbf[j] = (__bf16)chw[j];
        }
    } else if (bid < 672) {                    // bn0 sums (atomics into memset-zeroed stat)
        int pq = bid - 416;
        int c = pq & 63, q = pq >> 6;
        const float4* base = (const float4*)(x + (long)q * 8 * 65536 + (long)c * 1024);
        float s = 0.f, qq = 0.f;
        for (int i = tid; i < 2048; i += 256) {
            int b = i >> 8, t4 = i & 255;
            float4 v = base[b * 16384 + t4];
            s += v.x + v.y + v.z + v.w;
            qq = fmaf(v.x, v.x, qq); qq = fmaf(v.y, v.y, qq);
            qq = fmaf(v.z, v.z, qq); qq = fmaf(v.w, v.w, qq);
        }
        for (int off = 32; off; off >>= 1) { s += __shfl_down(s, off); qq += __shfl_down(qq, off); }
        __shared__ float ls[4], lq[4];
        int w = tid >> 6, lane = tid & 63;
        if (lane == 0) { ls[w] = s; lq[w] = qq; }
        __syncthreads();
        if (tid == 0) {
            unsafeAtomicAdd(sum0 + c, ls[0] + ls[1] + ls[2] + ls[3]);
            unsafeAtomicAdd(sq0 + c, lq[0] + lq[1] + lq[2] + lq[3]);
        }
    } else {                                   // bucket CSR fill (2048 blocks)
        int e = (bid - 672) * 256 + tid;
        int t = ei[Ec + e];
        int slot = atomicAdd(cursor + t, 1);
        bucket[t * 64 + slot] = ei[e];
    }
}

// ================= gemm1 with inline bn0: x slice -> LDS A-tile -> xlq/xrq ===
// block mb covers nodes mb*64..mb*64+63  (b = mb>>4, channels ci0..ci0+3)
// node n = b*1024 + ci*16 + (t>>6); features = 64 consecutive t of channel ci
__global__ __launch_bounds__(256) void gemm1_bn0(const float* __restrict__ x,
        const float* __restrict__ sum0, const float* __restrict__ sq0,
        const float* __restrict__ g0, const float* __restrict__ b0,
        const __bf16* __restrict__ wlrbf,
        unsigned short* __restrict__ xl16, unsigned short* __restrict__ xr16) {
    __shared__ __align__(16) __bf16 as_[64 * 72];   // 64 node-rows, stride 72 (2-way free)
    int tid = threadIdx.x;
    int mb = blockIdx.x;
    int b = mb >> 4, ci0 = (mb & 15) * 4;
    const float4* x4 = (const float4*)(x + (long)b * 65536 + (long)ci0 * 1024);
    #pragma unroll
    for (int it = 0; it < 4; it++) {               // iteration it == channel ci0+it
        int ci = ci0 + it;
        float mu = sum0[ci] * (1.f / 32768.f);
        float var = sq0[ci] * (1.f / 32768.f) - mu * mu;
        float sc = rsqrtf(var + 1e-5f) * g0[ci];
        float sh = b0[ci] - mu * sc;
        float4 v = x4[it * 256 + tid];             // t = tid*4
        int row = it * 16 + (tid >> 4);            // = node offset within block
        int col = (tid & 15) * 4;
        __bf16* p = as_ + row * 72 + col;
        p[0] = (__bf16)fmaf(v.x, sc, sh);
        p[1] = (__bf16)fmaf(v.y, sc, sh);
        p[2] = (__bf16)fmaf(v.z, sc, sh);
        p[3] = (__bf16)fmaf(v.w, sc, sh);
    }
    __syncthreads();
    int wv = tid >> 6, lane = tid & 63;
    int col = lane & 15, q = lane >> 4;
    int d0 = wv * 16;
    long mbase = (long)mb * 64;
    bf16x8 bfr[4][2];
    #pragma unroll
    for (int t = 0; t < 4; t++) {
        int j = d0 + t * 64 + col;
        #pragma unroll
        for (int ks = 0; ks < 2; ks++)
            bfr[t][ks] = *(const bf16x8*)(wlrbf + (long)j * 64 + ks * 32 + q * 8);
    }
    int d = d0 + col;
    for (int mt = 0; mt < 4; mt++) {
        const __bf16* ap = as_ + (mt * 16 + col) * 72;
        bf16x8 a0 = *(const bf16x8*)(ap + q * 8);
        bf16x8 a1 = *(const bf16x8*)(ap + 32 + q * 8);
        f32x4 acc[4];
        #pragma unroll
        for (int t = 0; t < 4; t++) { acc[t][0] = 0.f; acc[t][1] = 0.f; acc[t][2] = 0.f; acc[t][3] = 0.f; }
        #pragma unroll
        for (int t = 0; t < 4; t++) {
            acc[t] = __builtin_amdgcn_mfma_f32_16x16x32_bf16(a0, bfr[t][0], acc[t], 0, 0, 0);
            acc[t] = __builtin_amdgcn_mfma_f32_16x16x32_bf16(a1, bfr[t][1], acc[t], 0, 0, 0);
        }
        long r0 = mbase + mt * 16;
        #pragma unroll
        for (int reg = 0; reg < 4; reg++) {
            long rb = (r0 + q * 4 + reg) * 128;
            xl16[rb + d]      = (unsigned short)bfb(acc[0][reg]);
            xl16[rb + 64 + d] = (unsigned short)bfb(acc[1][reg]);
            xr16[rb + d]      = (unsigned short)bfb(acc[2][reg]);
            xr16[rb + 64 + d] = (unsigned short)bfb(acc[3][reg]);
        }
    }
}

// ================= conv role (bn0 inline, fp32 x -> LDS) =================
constexpr int XS_STRIDE = 72;          // bf16 units; 144B rows, 16B-aligned b128 frags

DEVINL void conv_role(int cid, const float* __restrict__ x,
        const float* __restrict__ sum0, const float* __restrict__ sq0,
        const float* __restrict__ g0, const float* __restrict__ b0,
        const __bf16* __restrict__ wcbf, const float* __restrict__ cb,
        float* __restrict__ res, __bf16* xs, float* scs, float* shs) {
    int tid = threadIdx.x;
    int tbase = (cid & 7) * 128;
    int cohalf = (cid >> 3) & 1;
    int b = cid >> 4;
    if (tid < 64) {
        float mu = sum0[tid] * (1.f / 32768.f);
        float var = sq0[tid] * (1.f / 32768.f) - mu * mu;
        float sc = rsqrtf(var + 1e-5f) * g0[tid];
        scs[tid] = sc; shs[tid] = b0[tid] - mu * sc;
    }
    __syncthreads();
    int w = tid >> 6, lane = tid & 63;
    const float* xb = x + (long)b * 65536;
    for (int cc = 0; cc < 16; cc++) {          // wave w stages channels w*16..w*16+15
        int ci = w * 16 + cc;
        float sc = scs[ci], sh = shs[ci];
        const float* xp = xb + ci * 1024 + tbase - 4;
        #pragma unroll
        for (int rp = 0; rp < 2; rp++) {
            int rr = rp * 64 + lane;
            int t = tbase - 4 + rr;
            float v = 0.f;
            if ((unsigned)t < 1024u) v = fmaf(xp[rr], sc, sh);
            xs[rr * XS_STRIDE + ci] = (__bf16)v;
        }
        if (lane < 8) {
            int rr = 128 + lane;
            int t = tbase - 4 + rr;
            float v = 0.f;
            if ((unsigned)t < 1024u) v = fmaf(xp[rr], sc, sh);
            xs[rr * XS_STRIDE + ci] = (__bf16)v;
        }
    }
    __syncthreads();
    int col = lane & 15, q = lane >> 4;
    int co0 = cohalf * 64 + w * 16;
    bf16x8 af[18];
    #pragma unroll
    for (int kk = 0; kk < 9; kk++)
        #pragma unroll
        for (int ks = 0; ks < 2; ks++)
            af[kk * 2 + ks] = *(const bf16x8*)(wcbf +
                ((long)kk * 8192 + (long)(co0 + col) * 64 + ks * 32 + q * 8));
    float bi0 = cb[co0 + q * 4], bi1 = cb[co0 + q * 4 + 1];
    float bi2 = cb[co0 + q * 4 + 2], bi3 = cb[co0 + q * 4 + 3];
    for (int nt = 0; nt < 8; nt++) {
        int t0 = tbase + nt * 16;
        f32x4 acc; acc[0] = bi0; acc[1] = bi1; acc[2] = bi2; acc[3] = bi3;
        #pragma unroll
        for (int kk = 0; kk < 9; kk++) {
            const __bf16* rp = xs + (nt * 16 + col + kk) * XS_STRIDE + q * 8;
            #pragma unroll
            for (int ks = 0; ks < 2; ks++) {
                bf16x8 bfx = *(const bf16x8*)(rp + ks * 32);   // 16B-aligned b128
                acc = __builtin_amdgcn_mfma_f32_16x16x32_bf16(af[kk * 2 + ks], bfx, acc, 0, 0, 0);
            }
        }
        long ob = (long)b * 131072 + (long)(co0 + q * 4) * 1024 + t0 + col;
        res[ob]        = fmaxf(acc[0], 0.f);
        res[ob + 1024] = fmaxf(acc[1], 0.f);
        res[ob + 2048] = fmaxf(acc[2], 0.f);
        res[ob + 3072] = fmaxf(acc[3], 0.f);
    }
}

// ================= gat role: 8 lanes/edge, per-head softmax; bf16 gout ======
DEVINL void gat_role(int wid, const uint4* __restrict__ xlq4,
        const uint4* __restrict__ xrq4,
        const int* __restrict__ cursor, const int* __restrict__ bucket,
        const float* __restrict__ att, unsigned* __restrict__ goutb) {
    int lane = threadIdx.x & 63;
    int g = lane >> 3, j = lane & 7;
    float av[16];
    #pragma unroll
    for (int k = 0; k < 16; k++) av[k] = att[16 * j + k];
    uint4 r0v = xrq4[(long)wid * 16 + j * 2];
    uint4 r1v = xrq4[(long)wid * 16 + j * 2 + 1];
    float xr[16];
    {
        unsigned ru[8] = {r0v.x, r0v.y, r0v.z, r0v.w, r1v.x, r1v.y, r1v.z, r1v.w};
        #pragma unroll
        for (int k = 0; k < 8; k++) { xr[2*k] = unpack_lo(ru[k]); xr[2*k+1] = unpack_hi(ru[k]); }
    }
    int cnt = cursor[wid];
    int s_all = bucket[wid * 64 + lane];
    float acc[16];
    #pragma unroll
    for (int k = 0; k < 16; k++) acc[k] = 0.f;
    float den = 0.f;
    int nit = (cnt + 8) >> 3;
    int sp = __shfl(s_all, g);
    sp = (g < cnt) ? sp : wid;
    uint4 p0 = xlq4[(long)sp * 16 + j * 2];
    uint4 p1 = xlq4[(long)sp * 16 + j * 2 + 1];
    for (int it = 0; it < nit; it++) {
        uint4 c0 = p0, c1 = p1;
        int icur = it * 8 + g;
        int inext = icur + 8;
        if (it + 1 < nit) {
            int sn = __shfl(s_all, inext & 63);
            sn = (inext < cnt) ? sn : wid;
            p0 = xlq4[(long)sn * 16 + j * 2];
            p1 = xlq4[(long)sn * 16 + j * 2 + 1];
        }
        unsigned uu[8] = {c0.x, c0.y, c0.z, c0.w, c1.x, c1.y, c1.z, c1.w};
        float xl[16];
        float w = 0.f;
        #pragma unroll
        for (int k = 0; k < 8; k++) {
            float lo = unpack_lo(uu[k]), hi = unpack_hi(uu[k]);
            xl[2*k] = lo; xl[2*k+1] = hi;
            float s0 = lo + xr[2*k]; s0 = fmaxf(s0, 0.2f * s0);
            float s1 = hi + xr[2*k+1]; s1 = fmaxf(s1, 0.2f * s1);
            w = fmaf(s1, av[2*k+1], fmaf(s0, av[2*k], w));
        }
        w += __shfl_xor(w, 1); w += __shfl_xor(w, 2);   // per-head 4-lane sum
        float e2 = (icur <= cnt) ? __expf(w) : 0.f;
        den += e2;
        #pragma unroll
        for (int k = 0; k < 16; k++) acc[k] = fmaf(e2, xl[k], acc[k]);
    }
    #pragma unroll
    for (int m = 8; m <= 32; m <<= 1) {
        den += __shfl_xor(den, m);
        #pragma unroll
        for (int k = 0; k < 16; k++) acc[k] += __shfl_xor(acc[k], m);
    }
    float rn = __builtin_amdgcn_rcpf(den);
    if (g == 0) {                              // lanes 0..7 write 32B each (bf16 pairs)
        #pragma unroll
        for (int c = 0; c < 2; c++) {
            uint4 o;
            o.x = pk2(acc[8*c]     * rn, acc[8*c + 1] * rn);
            o.y = pk2(acc[8*c + 2] * rn, acc[8*c + 3] * rn);
            o.z = pk2(acc[8*c + 4] * rn, acc[8*c + 5] * rn);
            o.w = pk2(acc[8*c + 6] * rn, acc[8*c + 7] * rn);
            *(uint4*)(goutb + (long)wid * 64 + 8 * j + 4 * c) = o;
        }
    }
}

// ================= conv U gat in one dispatch (conv hides under gather latency)
__global__ __launch_bounds__(256) void conv_gat(const float* __restrict__ x,
        const float* __restrict__ sum0, const float* __restrict__ sq0,
        const float* __restrict__ g0, const float* __restrict__ b0,
        const __bf16* __restrict__ wcbf, const float* __restrict__ cb,
        float* __restrict__ res,
        const uint4* __restrict__ xlq4, const uint4* __restrict__ xrq4,
        const int* __restrict__ cursor, const int* __restrict__ bucket,
        const float* __restrict__ att, unsigned* __restrict__ goutb) {
    __shared__ __align__(16) __bf16 xs[136 * XS_STRIDE];
    __shared__ float scs[64], shs[64];
    int bid = blockIdx.x;
    if (bid < 512)
        conv_role(bid, x, sum0, sq0, g0, b0, wcbf, cb, res, xs, scs, shs);
    else
        gat_role(((bid - 512) * 256 + (int)threadIdx.x) >> 6,
                 xlq4, xrq4, cursor, bucket, att, goutb);
}

// ================= bn stats over bf16-pair [N,64 uints] =================
__global__ __launch_bounds__(256) void bn_stats_bf(const unsigned* __restrict__ G,
        float* __restrict__ sum, float* __restrict__ sq) {
    int c = threadIdx.x & 63, sub = threadIdx.x >> 6;   // c: uint column (2 features)
    int r0 = blockIdx.x * 128;
    float sl = 0.f, sh = 0.f, ql = 0.f, qh = 0.f;
    for (int r = r0 + sub; r < r0 + 128; r += 4) {
        unsigned v = G[(long)r * 64 + c];
        float lo = unpack_lo(v), hi = unpack_hi(v);
        sl += lo; ql = fmaf(lo, lo, ql);
        sh += hi; qh = fmaf(hi, hi, qh);
    }
    __shared__ float A[256], B[256], C[256], D[256];
    A[threadIdx.x] = sl; B[threadIdx.x] = sh;
    C[threadIdx.x] = ql; D[threadIdx.x] = qh;
    __syncthreads();
    if (threadIdx.x < 64) {
        int t = threadIdx.x;
        float s_lo = A[t] + A[t + 64] + A[t + 128] + A[t + 192];
        float s_hi = B[t] + B[t + 64] + B[t + 128] + B[t + 192];
        float q_lo = C[t] + C[t + 64] + C[t + 128] + C[t + 192];
        float q_hi = D[t] + D[t + 64] + D[t + 128] + D[t + 192];
        unsafeAtomicAdd(sum + 2 * t,     s_lo);
        unsafeAtomicAdd(sum + 2 * t + 1, s_hi);
        unsafeAtomicAdd(sq  + 2 * t,     q_lo);
        unsafeAtomicAdd(sq  + 2 * t + 1, q_hi);
    }
}

// ================= cheb_fused: h2 in LDS, z = h2 @ chw^T (bf16 out), stats2 =================
__global__ __launch_bounds__(256) void cheb_fused(const unsigned* __restrict__ goutb,
        const float* __restrict__ res, const float* __restrict__ sum1,
        const float* __restrict__ sq1, const float* __restrict__ g1,
        const float* __restrict__ b1, const __bf16* __restrict__ chwbf,
        unsigned* __restrict__ zb, float* __restrict__ sum2, float* __restrict__ sq2) {
    __shared__ unsigned xsu[64 * 68];          // h2 tile, bf16 pairs, stride 68 uints
    __shared__ float scs[128], shs[128], cs[128], cq[128];
    int tid = threadIdx.x;
    if (tid < 128) {
        float mu = sum1[tid] * (1.f / 32768.f);
        float var = sq1[tid] * (1.f / 32768.f) - mu * mu;
        float rs = rsqrtf(var + 1e-5f);
        float sc = rs * g1[tid];
        scs[tid] = sc; shs[tid] = b1[tid] - mu * sc;
        cs[tid] = 0.f;
    } else cq[tid - 128] = 0.f;
    __syncthreads();
    long r0 = (long)blockIdx.x * 64;
    for (int i = tid; i < 2048; i += 256) {    // 64 rows x 32 quad-feature chunks
        int row = i >> 5, c4 = i & 31;
        long gidx = (r0 + row) * 32 + c4;
        uint2 gv = ((const uint2*)goutb)[gidx];
        float4 r = ((const float4*)res)[gidx];
        int f0 = c4 * 4;
        float v0 = unpack_lo(gv.x), v1 = unpack_hi(gv.x);
        float v2 = unpack_lo(gv.y), v3 = unpack_hi(gv.y);
        float o0 = r.x + fmaxf(fmaf(v0, scs[f0],     shs[f0]),     0.f);
        float o1 = r.y + fmaxf(fmaf(v1, scs[f0 + 1], shs[f0 + 1]), 0.f);
        float o2 = r.z + fmaxf(fmaf(v2, scs[f0 + 2], shs[f0 + 2]), 0.f);
        float o3 = r.w + fmaxf(fmaf(v3, scs[f0 + 3], shs[f0 + 3]), 0.f);
        xsu[row * 68 + c4 * 2]     = pk2(o0, o1);
        xsu[row * 68 + c4 * 2 + 1] = pk2(o2, o3);
    }
    __syncthreads();
    int wv = tid >> 6, lane = tid & 63;
    int col = lane & 15, q = lane >> 4;
    bf16x8 bfr[2][4];
    #pragma unroll
    for (int t = 0; t < 2; t++) {
        int jj = wv * 16 + t * 64 + col;
        #pragma unroll
        for (int ks = 0; ks < 4; ks++)
            bfr[t][ks] = *(const bf16x8*)(chwbf + (long)jj * 128 + ks * 32 + q * 8);
    }
    float ls0 = 0.f, ls1 = 0.f, lq0 = 0.f, lq1 = 0.f;
    bool evenc = (col & 1) == 0;
    int fpair0 = (wv * 16 + col) >> 1;         // uint index within z row (first half)
    for (int mt = 0; mt < 4; mt++) {
        const __bf16* ap = (const __bf16*)xsu + (mt * 16 + col) * 136;
        bf16x8 a[4];
        #pragma unroll
        for (int ks = 0; ks < 4; ks++)
            a[ks] = *(const bf16x8*)(ap + ks * 32 + q * 8);
        f32x4 acc[2];
        #pragma unroll
        for (int t = 0; t < 2; t++) { acc[t][0] = 0.f; acc[t][1] = 0.f; acc[t][2] = 0.f; acc[t][3] = 0.f; }
        #pragma unroll
        for (int t = 0; t < 2; t++)
            #pragma unroll
            for (int ks = 0; ks < 4; ks++)
                acc[t] = __builtin_amdgcn_mfma_f32_16x16x32_bf16(a[ks], bfr[t][ks], acc[t], 0, 0, 0);
        #pragma unroll
        for (int reg = 0; reg < 4; reg++) {
            float v0 = acc[0][reg], v1 = acc[1][reg];
            // stats from fp32 values (all lanes)
            ls0 += v0; lq0 = fmaf(v0, v0, lq0);
            ls1 += v1; lq1 = fmaf(v1, v1, lq1);
            // bf16-pair store: even col packs (own, col+1 partner)
            float n0 = __shfl_xor(v0, 1);
            float n1 = __shfl_xor(v1, 1);
            if (evenc) {
                long zrow = (r0 + mt * 16 + q * 4 + reg) * 64;
                zb[zrow + fpair0]      = pk2(v0, n0);
                zb[zrow + 32 + fpair0] = pk2(v1, n1);
            }
        }
    }
    int j0 = wv * 16 + col;
    atomicAdd(&cs[j0], ls0);      atomicAdd(&cs[j0 + 64], ls1);
    atomicAdd(&cq[j0], lq0);      atomicAdd(&cq[j0 + 64], lq1);
    __syncthreads();
    if (tid < 128) unsafeAtomicAdd(sum2 + tid, cs[tid]);
    else unsafeAtomicAdd(sq2 + tid - 128, cq[tid - 128]);
}

// ================= res + relu(bn(z bf16)) -> fp32 out =================
__global__ __launch_bounds__(256) void bn_res(const unsigned* __restrict__ zb,
        const float* __restrict__ res, const float* __restrict__ sum,
        const float* __restrict__ sq, const float* __restrict__ g,
        const float* __restrict__ bta, float* __restrict__ out) {
    __shared__ float scs[128], shs[128];
    int tid = threadIdx.x;
    if (tid < 128) {
        float mu = sum[tid] * (1.f / 32768.f);
        float var = sq[tid] * (1.f / 32768.f) - mu * mu;
        float rs = rsqrtf(var + 1e-5f);
        float sc = rs * g[tid];
        scs[tid] = sc; shs[tid] = bta[tid] - mu * sc;
    }
    __syncthreads();
    int idx = blockIdx.x * 256 + tid;
    int f0 = (idx & 31) * 4;
    uint2 zv = ((const uint2*)zb)[idx];
    float4 r = ((const float4*)res)[idx];
    float v0 = unpack_lo(zv.x), v1 = unpack_hi(zv.x);
    float v2 = unpack_lo(zv.y), v3 = unpack_hi(zv.y);
    float4 o;
    o.x = r.x + fmaxf(fmaf(v0, scs[f0],     shs[f0]),     0.f);
    o.y = r.y + fmaxf(fmaf(v1, scs[f0 + 1], shs[f0 + 1]), 0.f);
    o.z = r.z + fmaxf(fmaf(v2, scs[f0 + 2], shs[f0 + 2]), 0.f);
    o.w = r.w + fmaxf(fmaf(v3, scs[f0 + 3], shs[f0 + 3]), 0.f);
    ((float4*)out)[idx] = o;
}

extern "C" void kernel_launch(void* const* d_in, const int* in_sizes, int n_in,
                              void* d_out, int out_size, void* d_ws, size_t ws_size,
                              hipStream_t stream) {
    const float* x   = (const float*)d_in[0];
    const int*   ei  = (const int*)d_in[1];
    const float* g0  = (const float*)d_in[2];
    const float* b0  = (const float*)d_in[3];
    const float* cw  = (const float*)d_in[4];
    const float* cb  = (const float*)d_in[5];
    const float* wl  = (const float*)d_in[6];
    const float* wr  = (const float*)d_in[7];
    const float* att = (const float*)d_in[8];
    // d_in[9] = gat_bias: cancels exactly inside the following bn2d -> unused
    const float* g1  = (const float*)d_in[10];
    const float* b1  = (const float*)d_in[11];
    const float* chw = (const float*)d_in[12];
    // d_in[13] = cheb_b: cancels inside the following bn2d -> unused
    float* out = (float*)d_out;

    float* ws = (float*)d_ws;
    float*    res   = ws + O_RES;
    unsigned* goutb = (unsigned*)(ws + O_GOUT);
    unsigned* xlq   = (unsigned*)(ws + O_XLQ);
    unsigned* xrq   = (unsigned*)(ws + O_XRQ);
    unsigned* zb    = (unsigned*)(ws + O_Z);
    __bf16*   wcbf  = (__bf16*)(ws + O_WCBF);
    __bf16*   wlrbf = (__bf16*)(ws + O_WLR);
    __bf16*   chwbf = (__bf16*)(ws + O_CHB);
    float*    st    = ws + O_STAT;
    int*      cursor = (int*)(ws + O_CUR);
    int*      bucket = (int*)(ws + O_BUCK);
    float *sum0 = st,       *sq0 = st + 64;
    float *sum1 = st + 128, *sq1 = st + 256;
    float *sum2 = st + 384, *sq2 = st + 512;

    // one memset covers stat block (4KB) + cursor (128KB), contiguous
    hipMemsetAsync(st, 0, (size_t)(1024 + 32768) * 4, stream);

    // prep_w U bn0_sums U bucket_fill
    setup<<<2720, 256, 0, stream>>>(x, cw, wl, wr, chw, ei,
                                    wcbf, wlrbf, chwbf, sum0, sq0, cursor, bucket);
    // gemm1 with inline bn0 (direct from x) -> xlq/xrq
    gemm1_bn0<<<512, 256, 0, stream>>>(x, sum0, sq0, g0, b0, wlrbf,
                                       (unsigned short*)xlq, (unsigned short*)xrq);
    // conv1d+relu->res (bn0 inline) U fused GATv2 -> bf16 gout, one dispatch
    conv_gat<<<8704, 256, 0, stream>>>(x, sum0, sq0, g0, b0, wcbf, cb, res,
                                       (const uint4*)xlq, (const uint4*)xrq,
                                       cursor, bucket, att, goutb);
    // bn1 stats (bf16 input)
    bn_stats_bf<<<256, 256, 0, stream>>>(goutb, sum1, sq1);
    // h2 in LDS -> cheb GEMM -> z (bf16) + stats2
    cheb_fused<<<512, 256, 0, stream>>>(goutb, res, sum1, sq1, g1, b1, chwbf,
                                        zb, sum2, sq2);
    // bn + relu + residual -> out
    bn_res<<<4096, 256, 0, stream>>>(zb, res, sum2, sq2, g1, b1, out);
}